// Round 12
// baseline (660.717 us; speedup 1.0000x reference)
//
#include <hip/hip_runtime.h>
#include <stdint.h>

#define HID 512
#define THREE_H 1536
#define ADIM 256
#define NVOC 10000
#define TEnc 256
#define TDec 128

typedef float f32x4 __attribute__((ext_vector_type(4)));
typedef __bf16 bf16x8 __attribute__((ext_vector_type(8)));

__device__ __forceinline__ unsigned short f2bf(float f) {
  union { float f; unsigned u; } v; v.f = f;
  unsigned r = v.u + 0x7FFFu + ((v.u >> 16) & 1u);
  return (unsigned short)(r >> 16);
}
__device__ __forceinline__ float sigmoidf_(float x) { return 1.f / (1.f + __expf(-x)); }
__device__ __forceinline__ float tanh_fast(float x) {
  float ax = fabsf(x);
  float e = __expf(ax + ax);
  float t = 1.f - 2.f / (e + 1.f);
  return copysignf(t, x);
}

// Exchange ledger (measured, r2-r11): cross-WG producer->consumer handoff on
// gfx950 is ~2.8-3.0us REGARDLESS of mechanism:
//   sys-scope stores+polls (r6) 2.9us; broadcast stores (r7) WORSE (+1.7us,
//   store serialization); line-spreading (r8) neutral; poller-rate cut (r9)
//   neutral; no-sc1 atomics (r10) not a meeting point (0% visibility);
//   agent-scope atomic RMW exchange (r11) neutral.
// => 128 sequential handoffs ~= 360us is STRUCTURAL for this scan shape.
// r4 ERRATUM stands: sc0-only loads never observe remote stores (stale L1).
__device__ __forceinline__ void st_u64_sys(unsigned long long* p, unsigned long long v) {
  asm volatile("global_store_dwordx2 %0, %1, off sc0 sc1" :: "v"(p), "v"(v) : "memory");
}
__device__ __forceinline__ unsigned long long ld_u64_sys(const unsigned long long* p) {
  unsigned long long a;
  asm volatile("global_load_dwordx2 %0, %1, off sc0 sc1\n\ts_waitcnt vmcnt(0)"
               : "=&v"(a) : "v"(p) : "memory");
  return a;
}

#define GLDS16(gp, lp)                                                                 \
  __builtin_amdgcn_global_load_lds((const __attribute__((address_space(1))) void*)(gp),\
                                   (__attribute__((address_space(3))) void*)(lp), 16, 0, 0)

// ---------------- fp32 -> bf16 convert (x and y fused) ----------------
__global__ void cvt_xy(const float* __restrict__ x, const float* __restrict__ y,
                       unsigned short* __restrict__ xb, unsigned short* __restrict__ yb) {
  int i = (blockIdx.x * blockDim.x + threadIdx.x) * 4;
  const float* src;
  unsigned short* dst;
  int j;
  if (i < TEnc * HID) { src = x; dst = xb; j = i; }
  else { src = y; dst = yb; j = i - TEnc * HID; }
  float4 v = *(const float4*)(src + j);
  ushort4 o;
  o.x = f2bf(v.x); o.y = f2bf(v.y); o.z = f2bf(v.z); o.w = f2bf(v.w);
  *(ushort4*)(dst + j) = o;
}

// ---------------- BT-GEMM: C[M,N] = A[M,K](bf16) * B[N,K]^T(f32->bf16) + bias ----------------
template <int BN, int BK>
__global__ __launch_bounds__(256, 1) void gemm_bt(
    const unsigned short* __restrict__ Abf, const float* __restrict__ B,
    const float* __restrict__ bias, float* __restrict__ C, unsigned short* __restrict__ Cbf,
    int M, int N, int K) {
  constexpr int NF = BN / 16;
  constexpr int B4 = BN * BK / 1024;
  constexpr int AG = BK / 16;
  constexpr int KK = BK / 32;
  extern __shared__ char smem[];
  unsigned short* Al0 = (unsigned short*)smem;
  unsigned short* Al1 = Al0 + 128 * BK;
  unsigned short* Bl0 = Al1 + 128 * BK;
  unsigned short* Bl1 = Bl0 + BN * BK;

  const int tid = threadIdx.x;
  const int lane = tid & 63;
  const int wid = tid >> 6;
  const int m0 = blockIdx.x * 128;
  const int n0 = blockIdx.y * BN;
  const int NT = K / BK;

  float4 breg[B4];
  f32x4 acc[2][NF];
#pragma unroll
  for (int i = 0; i < 2; ++i)
#pragma unroll
    for (int j = 0; j < NF; ++j) acc[i][j] = (f32x4){0.f, 0.f, 0.f, 0.f};

  auto stageA = [&](int t, unsigned short* dst) {
    const unsigned short* Ab = Abf + (size_t)m0 * K + (size_t)t * BK;
#pragma unroll
    for (int g = 0; g < AG; ++g) {
      int elem = g * 2048 + tid * 8;
      int arow = elem / BK;
      int acol = elem - arow * BK;
      GLDS16(Ab + (size_t)arow * K + acol, (char*)dst + g * 4096 + wid * 1024);
    }
  };
  auto loadB = [&](int t) {
    const float* Bb = B + (size_t)t * BK;
#pragma unroll
    for (int p = 0; p < B4; ++p) {
      int e = (p * 256 + tid) * 4;
      int brow = e / BK;
      int bcol = e - brow * BK;
      int grow = n0 + brow;
      if (grow > N - 1) grow = N - 1;
      breg[p] = *(const float4*)(Bb + (size_t)grow * K + bcol);
    }
  };
  auto writeB = [&](unsigned short* dst) {
#pragma unroll
    for (int p = 0; p < B4; ++p) {
      ushort4 o;
      o.x = f2bf(breg[p].x); o.y = f2bf(breg[p].y);
      o.z = f2bf(breg[p].z); o.w = f2bf(breg[p].w);
      *(ushort4*)((char*)dst + (p * 256 + tid) * 8) = o;
    }
  };

  stageA(0, Al0);
  loadB(0);
  for (int t = 0; t < NT; ++t) {
    unsigned short* Ac = (t & 1) ? Al1 : Al0;
    unsigned short* Bc = (t & 1) ? Bl1 : Bl0;
    asm volatile("s_waitcnt vmcnt(0)" ::: "memory");
    writeB(Bc);
    __syncthreads();
    if (t + 1 < NT) {
      stageA(t + 1, (t & 1) ? Al0 : Al1);
      loadB(t + 1);
    }
    const int r0 = lane & 15;
    const int kb = (lane >> 4) * 8;
#pragma unroll
    for (int kk = 0; kk < KK; ++kk) {
      int ko = kk * 32 + kb;
      bf16x8 a0 = *(const bf16x8*)(Ac + (wid * 32 + r0) * BK + ko);
      bf16x8 a1 = *(const bf16x8*)(Ac + (wid * 32 + 16 + r0) * BK + ko);
#pragma unroll
      for (int nf = 0; nf < NF; ++nf) {
        bf16x8 bb = *(const bf16x8*)(Bc + (nf * 16 + r0) * BK + ko);
        acc[0][nf] = __builtin_amdgcn_mfma_f32_16x16x32_bf16(a0, bb, acc[0][nf], 0, 0, 0);
        acc[1][nf] = __builtin_amdgcn_mfma_f32_16x16x32_bf16(a1, bb, acc[1][nf], 0, 0, 0);
      }
    }
  }
  const int cc = lane & 15;
  const int rq = (lane >> 4) * 4;
#pragma unroll
  for (int mi = 0; mi < 2; ++mi) {
    int row = m0 + wid * 32 + mi * 16 + rq;
#pragma unroll
    for (int nf = 0; nf < NF; ++nf) {
      int col = n0 + nf * 16 + cc;
      if (col < N) {
        float bv = bias ? bias[col] : 0.f;
#pragma unroll
        for (int j = 0; j < 4; ++j) {
          float v = acc[mi][nf][j] + bv;
          if (C) C[(size_t)(row + j) * N + col] = v;
          if (Cbf) Cbf[(size_t)(row + j) * N + col] = f2bf(v);
        }
      }
    }
  }
}

// ---------------- encoder GEMM with fused GRU gates (h_prev = 0) ----------------
__global__ __launch_bounds__(256, 1) void gemm_enc(
    const unsigned short* __restrict__ Abf, const float* __restrict__ Wi,
    const float* __restrict__ bi, const float* __restrict__ bh,
    float* __restrict__ encH, unsigned short* __restrict__ encHbf) {
  constexpr int BN = 96, BK = 128, NF = 6, B4 = 12, AG = 8, KK = 4, K = 512;
  extern __shared__ char smem[];
  unsigned short* Al0 = (unsigned short*)smem;
  unsigned short* Al1 = Al0 + 128 * BK;
  unsigned short* Bl0 = Al1 + 128 * BK;
  unsigned short* Bl1 = Bl0 + BN * BK;

  const int tid = threadIdx.x;
  const int lane = tid & 63;
  const int wid = tid >> 6;
  const int m0 = blockIdx.x * 128;
  const int n0g = blockIdx.y * 32;
  const int NT = K / BK;

  float4 breg[B4];
  f32x4 acc[2][NF];
#pragma unroll
  for (int i = 0; i < 2; ++i)
#pragma unroll
    for (int j = 0; j < NF; ++j) acc[i][j] = (f32x4){0.f, 0.f, 0.f, 0.f};

  auto stageA = [&](int t, unsigned short* dst) {
    const unsigned short* Ab = Abf + (size_t)m0 * K + (size_t)t * BK;
#pragma unroll
    for (int g = 0; g < AG; ++g) {
      int elem = g * 2048 + tid * 8;
      int arow = elem >> 7;
      int acol = elem & 127;
      GLDS16(Ab + (size_t)arow * K + acol, (char*)dst + g * 4096 + wid * 1024);
    }
  };
  auto loadB = [&](int t) {
    const float* Bb = Wi + (size_t)t * BK;
#pragma unroll
    for (int p = 0; p < B4; ++p) {
      int e = (p * 256 + tid) * 4;
      int brow = e >> 7;
      int bcol = e & 127;
      int grow = (brow >> 5) * HID + n0g + (brow & 31);
      breg[p] = *(const float4*)(Bb + (size_t)grow * K + bcol);
    }
  };
  auto writeB = [&](unsigned short* dst) {
#pragma unroll
    for (int p = 0; p < B4; ++p) {
      ushort4 o;
      o.x = f2bf(breg[p].x); o.y = f2bf(breg[p].y);
      o.z = f2bf(breg[p].z); o.w = f2bf(breg[p].w);
      *(ushort4*)((char*)dst + (p * 256 + tid) * 8) = o;
    }
  };

  stageA(0, Al0);
  loadB(0);
  for (int t = 0; t < NT; ++t) {
    unsigned short* Ac = (t & 1) ? Al1 : Al0;
    unsigned short* Bc = (t & 1) ? Bl1 : Bl0;
    asm volatile("s_waitcnt vmcnt(0)" ::: "memory");
    writeB(Bc);
    __syncthreads();
    if (t + 1 < NT) {
      stageA(t + 1, (t & 1) ? Al0 : Al1);
      loadB(t + 1);
    }
    const int r0 = lane & 15;
    const int kb = (lane >> 4) * 8;
#pragma unroll
    for (int kk = 0; kk < KK; ++kk) {
      int ko = kk * 32 + kb;
      bf16x8 a0 = *(const bf16x8*)(Ac + (wid * 32 + r0) * BK + ko);
      bf16x8 a1 = *(const bf16x8*)(Ac + (wid * 32 + 16 + r0) * BK + ko);
#pragma unroll
      for (int nf = 0; nf < NF; ++nf) {
        bf16x8 bb = *(const bf16x8*)(Bc + (nf * 16 + r0) * BK + ko);
        acc[0][nf] = __builtin_amdgcn_mfma_f32_16x16x32_bf16(a0, bb, acc[0][nf], 0, 0, 0);
        acc[1][nf] = __builtin_amdgcn_mfma_f32_16x16x32_bf16(a1, bb, acc[1][nf], 0, 0, 0);
      }
    }
  }
  const int cc = lane & 15;
  const int rq = (lane >> 4) * 4;
#pragma unroll
  for (int mi = 0; mi < 2; ++mi) {
    int row = m0 + wid * 32 + mi * 16 + rq;
#pragma unroll
    for (int nfj = 0; nfj < 2; ++nfj) {
      int j = n0g + nfj * 16 + cc;
      float br_ = bi[j] + bh[j];
      float bz_ = bi[HID + j] + bh[HID + j];
      float bin_ = bi[2 * HID + j];
      float bhn_ = bh[2 * HID + j];
#pragma unroll
      for (int jj = 0; jj < 4; ++jj) {
        float r = sigmoidf_(acc[mi][nfj][jj] + br_);
        float z = sigmoidf_(acc[mi][nfj + 2][jj] + bz_);
        float n = tanh_fast(acc[mi][nfj + 4][jj] + bin_ + r * bhn_);
        float h = (1.f - z) * n;
        encH[(size_t)(row + jj) * HID + j] = h;
        encHbf[(size_t)(row + jj) * HID + j] = f2bf(h);
      }
    }
  }
}

// ---------------- sequential GRU scan (r6 champion) + L3 warmers ----------------
// WGs 0-31: EXACT r6 scan (sys-scope packed mailbox, proven 601us config —
// at the measured ~2.9us/step cross-WG handoff floor).
// WGs 32-240: THROTTLED L3 warmers on otherwise-idle CUs — stream-touch
// W2's first ~117MB then all of W1 (82MB) into Infinity Cache at ~1.1TB/s
// aggregate (s_sleep(127) every 4th iter; r5 showed SATURATING co-traffic
// inflates exchange RTT — this is 6x gentler). Read-only, no sync, no
// deadlock possible. W1 warmed last so it is freshest for the next kernel.
__global__ __launch_bounds__(256, 1) void gru_scan(
    const float* __restrict__ Whd, const float* __restrict__ bhd,
    const float* __restrict__ giY, const float* __restrict__ h0,
    unsigned long long* __restrict__ hx,
    unsigned short* __restrict__ decSbf, unsigned short* __restrict__ concatbf,
    const float* __restrict__ W1w, const float* __restrict__ W2w) {
  __shared__ float hl[548];   // word w -> slot w + ((w>>7)<<2); 544 used
  __shared__ float dots[48];
  const int tid = threadIdx.x;
  const int lane = tid & 63, wid = tid >> 6;
  const int g = blockIdx.x;

  if (g >= 32) {
    // ---- warmer ----
    const int widx = g - 32;  // 0..208
    float keep = 0.f;
    {
      const float4* s2 = (const float4*)(W2w + (size_t)widx * 7 * 20000);
      const int n4 = 7 * 20000 / 4;  // 35000 -> 209*7=1463 rows ~ 117MB
      for (int i = tid; i < n4; i += 256) {
        float4 v = s2[i];
        keep += v.x + v.y + v.z + v.w;
        if ((i & 1023) == tid) __builtin_amdgcn_s_sleep(127);
      }
    }
    {
      const float4* s1 = (const float4*)(W1w + (size_t)widx * 96 * 1024);
      const int n4 = 96 * 1024 / 4;  // 24576 -> 209*96 >= 20000 rows (82MB)
      const size_t base4 = (size_t)widx * 96 * 1024 / 4;
      const size_t lim4 = (size_t)20000 * 1024 / 4;
      for (int i = tid; i < n4; i += 256) {
        if (base4 + i >= lim4) break;
        float4 v = s1[i];
        keep += v.x + v.y + v.z + v.w;
        if ((i & 1023) == tid) __builtin_amdgcn_s_sleep(127);
      }
    }
    asm volatile("" :: "v"(keep));
    return;
  }

  // ---- scan worker (r6 EXACT) ----
  const int row16 = lane & 15;
  const int q = lane >> 4;
  float4 wreg[32];
  {
    int wrow = (wid < 3) ? wid : 0;
    const float* wr = Whd + ((size_t)wrow * HID + (size_t)g * 16 + row16) * HID + q * 128;
#pragma unroll
    for (int i = 0; i < 32; ++i) wreg[i] = *(const float4*)(wr + i * 4);
  }
  float bhr = 0.f, bhz = 0.f, bhn = 0.f, hreg = 0.f;
  if (wid == 3 && lane < 16) {
    int jj = g * 16 + lane;
    bhr = bhd[jj]; bhz = bhd[HID + jj]; bhn = bhd[2 * HID + jj];
    hreg = h0[jj];
  }
  {
    int w0 = tid * 2, w1 = tid * 2 + 1;
    hl[w0 + ((w0 >> 7) << 2)] = h0[w0];
    hl[w1 + ((w1 >> 7) << 2)] = h0[w1];
  }
  __syncthreads();

  for (int t = 0; t < TDec; ++t) {
    float gir = 0.f, giz = 0.f, gin = 0.f;
    if (wid < 3) {
      const float4* hp = (const float4*)hl;
      const int hb = q * 33;
      float p0 = 0.f, p1 = 0.f, p2 = 0.f, p3 = 0.f;
#pragma unroll
      for (int i = 0; i < 32; i += 4) {
        float4 ha = hp[hb + i], hv = hp[hb + i + 1], hc = hp[hb + i + 2], hd = hp[hb + i + 3];
        float4 wa = wreg[i], wb = wreg[i + 1], wc = wreg[i + 2], wd = wreg[i + 3];
        p0 += wa.x * ha.x + wa.y * ha.y + wa.z * ha.z + wa.w * ha.w;
        p1 += wb.x * hv.x + wb.y * hv.y + wb.z * hv.z + wb.w * hv.w;
        p2 += wc.x * hc.x + wc.y * hc.y + wc.z * hc.z + wc.w * hc.w;
        p3 += wd.x * hd.x + wd.y * hd.y + wd.z * hd.z + wd.w * hd.w;
      }
      float p = (p0 + p1) + (p2 + p3);
      p += __shfl_xor(p, 16);
      p += __shfl_xor(p, 32);
      if (lane < 16) dots[wid * 16 + lane] = p;
    } else if (lane < 16) {
      int jj = g * 16 + lane;
      const float* gi = giY + (size_t)t * THREE_H;
      gir = gi[jj]; giz = gi[HID + jj]; gin = gi[2 * HID + jj];  // hidden under dots
    }
    __syncthreads();  // dots ready; hl(t) reads done
    unsigned long long* hxB = hx + (size_t)(t & 1) * 256;
    if (wid == 3 && lane < 16) {
      int jj = g * 16 + lane;
      float r = sigmoidf_(gir + dots[lane] + bhr);
      float z = sigmoidf_(giz + dots[16 + lane] + bhz);
      float n = tanh_fast(gin + r * (dots[32 + lane] + bhn));
      float hn = (1.f - z) * n + z * hreg;
      hreg = hn;
      unsigned short hb16 = f2bf(hn);
      unsigned short hb_up = (unsigned short)__shfl_xor((int)hb16, 1);
      if ((lane & 1) == 0) {
        unsigned long long w = ((unsigned long long)(unsigned)(t + 1) << 32) |
                               ((unsigned)hb_up << 16) | (unsigned)hb16;
        st_u64_sys(hxB + g * 8 + (lane >> 1), w);
      }
      decSbf[(size_t)t * HID + jj] = hb16;
      concatbf[(size_t)t * 2 * HID + HID + jj] = hb16;
    }
    if (t == TDec - 1) break;
    {
      const unsigned long long* p0 = hxB + tid;
      const unsigned tag = (unsigned)(t + 1);
      unsigned long long v;
      int guard = 0;
      do { v = ld_u64_sys(p0); } while ((unsigned)(v >> 32) != tag && ++guard < (1 << 20));
      int w0 = tid * 2, w1 = tid * 2 + 1;
      hl[w0 + ((w0 >> 7) << 2)] = __uint_as_float(((unsigned)v & 0xFFFFu) << 16);
      hl[w1 + ((w1 >> 7) << 2)] = __uint_as_float((((unsigned)v >> 16) & 0xFFFFu) << 16);
    }
    __syncthreads();
  }
}

// ---------------- attention: fused decP + scores + softmax + context ----------------
__global__ __launch_bounds__(256) void attn_ctx(const float* __restrict__ encP,
                                                const unsigned short* __restrict__ decSbf,
                                                const float* __restrict__ Ws,
                                                const float* __restrict__ battn,
                                                const float* __restrict__ vattn,
                                                const float* __restrict__ encH,
                                                unsigned short* __restrict__ concatbf) {
  __shared__ float dp[ADIM], vv[ADIM], pl[TEnc], dsr[HID];
  __shared__ float red[8];
  const int t = blockIdx.x, tid = threadIdx.x;
  // decS row -> LDS f32
  {
    unsigned short u0 = decSbf[(size_t)t * HID + tid];
    unsigned short u1 = decSbf[(size_t)t * HID + tid + 256];
    dsr[tid] = __uint_as_float((unsigned)u0 << 16);
    dsr[tid + 256] = __uint_as_float((unsigned)u1 << 16);
  }
  if (tid < 64) *(float4*)(vv + tid * 4) = *(const float4*)(vattn + tid * 4);
  __syncthreads();
  // fused decP[a]: dot(Ws[a,:], decS[t,:]) + b_attn[a]
  {
    const float4* wr = (const float4*)(Ws + (size_t)tid * HID);
    const float4* hr = (const float4*)dsr;
    float s0 = 0.f, s1 = 0.f, s2 = 0.f, s3 = 0.f;
#pragma unroll 4
    for (int k = 0; k < 128; k += 4) {
      float4 w0 = wr[k], w1 = wr[k + 1], w2 = wr[k + 2], w3 = wr[k + 3];
      float4 h0 = hr[k], h1 = hr[k + 1], h2 = hr[k + 2], h3 = hr[k + 3];
      s0 += w0.x * h0.x + w0.y * h0.y + w0.z * h0.z + w0.w * h0.w;
      s1 += w1.x * h1.x + w1.y * h1.y + w1.z * h1.z + w1.w * h1.w;
      s2 += w2.x * h2.x + w2.y * h2.y + w2.z * h2.z + w2.w * h2.w;
      s3 += w3.x * h3.x + w3.y * h3.y + w3.z * h3.z + w3.w * h3.w;
    }
    dp[tid] = (s0 + s1) + (s2 + s3) + battn[tid];
  }
  __syncthreads();
  float s = 0.f;
  const float* ep = encP + (size_t)tid * ADIM;
#pragma unroll 4
  for (int a = 0; a < ADIM; a += 4) {
    float4 e4 = *(const float4*)(ep + a);
    s += vv[a] * tanh_fast(e4.x + dp[a]);
    s += vv[a + 1] * tanh_fast(e4.y + dp[a + 1]);
    s += vv[a + 2] * tanh_fast(e4.z + dp[a + 2]);
    s += vv[a + 3] * tanh_fast(e4.w + dp[a + 3]);
  }
  float m = s;
#pragma unroll
  for (int off = 32; off; off >>= 1) m = fmaxf(m, __shfl_xor(m, off));
  if ((tid & 63) == 0) red[tid >> 6] = m;
  __syncthreads();
  m = fmaxf(fmaxf(red[0], red[1]), fmaxf(red[2], red[3]));
  float p = __expf(s - m);
  pl[tid] = p;
  float sum = p;
#pragma unroll
  for (int off = 32; off; off >>= 1) sum += __shfl_xor(sum, off);
  if ((tid & 63) == 0) red[4 + (tid >> 6)] = sum;
  __syncthreads();
  float inv = 1.f / (red[4] + red[5] + red[6] + red[7]);
  float a0 = 0.f, a1 = 0.f;
  for (int e = 0; e < TEnc; ++e) {
    float pe = pl[e];
    a0 += pe * encH[(size_t)e * HID + tid];
    a1 += pe * encH[(size_t)e * HID + tid + 256];
  }
  concatbf[(size_t)t * 2 * HID + tid] = f2bf(a0 * inv);
  concatbf[(size_t)t * 2 * HID + tid + 256] = f2bf(a1 * inv);
}

extern "C" void kernel_launch(void* const* d_in, const int* in_sizes, int n_in,
                              void* d_out, int out_size, void* d_ws, size_t ws_size,
                              hipStream_t stream) {
  const float* x = (const float*)d_in[0];
  const float* y = (const float*)d_in[1];
  const float* Wi_e = (const float*)d_in[2];
  const float* bi_e = (const float*)d_in[4];
  const float* bh_e = (const float*)d_in[5];
  const float* Wi_d = (const float*)d_in[6];
  const float* Wh_d = (const float*)d_in[7];
  const float* bi_d = (const float*)d_in[8];
  const float* bh_d = (const float*)d_in[9];
  const float* Wh_attn = (const float*)d_in[10];
  const float* Ws_attn = (const float*)d_in[11];
  const float* b_attn = (const float*)d_in[12];
  const float* v_attn = (const float*)d_in[13];
  const float* W1 = (const float*)d_in[14];
  const float* b1 = (const float*)d_in[15];
  const float* W2 = (const float*)d_in[16];
  const float* b2 = (const float*)d_in[17];
  float* out = (float*)d_out;

  char* ws = (char*)d_ws;
  size_t off = 0;
  auto alloc = [&](size_t bytes) {
    char* p = ws + off;
    off += (bytes + 255) & ~(size_t)255;
    return p;
  };
  char* ctrl = alloc(4096);
  unsigned long long* hx = (unsigned long long*)ctrl;  // 2*256*8 = 4096
  unsigned short* Xbf = (unsigned short*)alloc((size_t)TEnc * HID * 2);
  unsigned short* Ybf = (unsigned short*)alloc((size_t)TDec * HID * 2);
  float* giY = (float*)alloc((size_t)TDec * THREE_H * 4);
  float* encH = (float*)alloc((size_t)TEnc * HID * 4);
  unsigned short* encHbf = (unsigned short*)alloc((size_t)TEnc * HID * 2);
  float* encP = (float*)alloc((size_t)TEnc * ADIM * 4);
  unsigned short* decSbf = (unsigned short*)alloc((size_t)TDec * HID * 2);
  unsigned short* concatbf = (unsigned short*)alloc((size_t)TDec * 2 * HID * 2);
  unsigned short* out1bf = (unsigned short*)alloc((size_t)TDec * 20000 * 2);

  hipMemsetAsync(ctrl, 0, 4096, stream);  // zero exchange tags

  auto* g32 = gemm_bt<32, 128>;
  auto* g80 = gemm_bt<80, 128>;
  auto* g64 = gemm_bt<64, 160>;
  const int smem32 = (128 + 32) * 128 * 2 * 2;      // 81920
  const int smem80 = (128 + 80) * 128 * 2 * 2;      // 106496
  const int smem64 = (128 + 64) * 160 * 2 * 2;      // 122880
  const int smemEnc = (128 + 96) * 128 * 2 * 2;     // 114688
  hipFuncSetAttribute((const void*)g32, hipFuncAttributeMaxDynamicSharedMemorySize, smem32);
  hipFuncSetAttribute((const void*)g80, hipFuncAttributeMaxDynamicSharedMemorySize, smem80);
  hipFuncSetAttribute((const void*)g64, hipFuncAttributeMaxDynamicSharedMemorySize, smem64);
  hipFuncSetAttribute((const void*)gemm_enc, hipFuncAttributeMaxDynamicSharedMemorySize, smemEnc);

  cvt_xy<<<(TEnc + TDec) * HID / 1024, 256, 0, stream>>>(x, y, Xbf, Ybf);
  // encoder GEMM + fused gates
  gemm_enc<<<dim3(2, 16), 256, smemEnc, stream>>>(Xbf, Wi_e, bi_e, bh_e, encH, encHbf);
  // encP = encH @ Wh_attn^T
  g32<<<dim3(2, 8), 256, smem32, stream>>>(encHbf, Wh_attn, nullptr, encP, nullptr, 256, 256, 512);
  // giY = Ybf @ Wi_d^T + bi_d
  g32<<<dim3(1, 48), 256, smem32, stream>>>(Ybf, Wi_d, bi_d, giY, nullptr, 128, 1536, 512);
  // sequential decoder scan (WGs 0-31) + throttled L3 warmers (WGs 32-240)
  gru_scan<<<241, 256, 0, stream>>>(Wh_d, bh_d, giY, encH + 255 * HID, hx,
                                    decSbf, concatbf, W1, W2);
  // fused decP + attention + context
  attn_ctx<<<TDec, 256, 0, stream>>>(encP, decSbf, Ws_attn, b_attn, v_attn, encH, concatbf);
  // out1 = concat @ W1^T + b1 (store bf16; W1 is L3-warm)
  g80<<<dim3(1, 250), 256, smem80, stream>>>(concatbf, W1, b1, nullptr, out1bf, 128, 20000, 1024);
  // out = out1 @ W2^T + b2 (f32 B-stream, 800MB; first ~117MB L3-warm)
  g64<<<dim3(1, 157), 256, smem64, stream>>>(out1bf, W2, b2, out, nullptr, 128, NVOC, 20000);
}

// Round 13
// 611.858 us; speedup vs baseline: 1.0799x; 1.0799x over previous
//
#include <hip/hip_runtime.h>
#include <stdint.h>

#define HID 512
#define THREE_H 1536
#define ADIM 256
#define NVOC 10000
#define TEnc 256
#define TDec 128

typedef float f32x4 __attribute__((ext_vector_type(4)));
typedef __bf16 bf16x8 __attribute__((ext_vector_type(8)));

__device__ __forceinline__ unsigned short f2bf(float f) {
  union { float f; unsigned u; } v; v.f = f;
  unsigned r = v.u + 0x7FFFu + ((v.u >> 16) & 1u);
  return (unsigned short)(r >> 16);
}
__device__ __forceinline__ float sigmoidf_(float x) { return 1.f / (1.f + __expf(-x)); }
__device__ __forceinline__ float tanh_fast(float x) {
  float ax = fabsf(x);
  float e = __expf(ax + ax);
  float t = 1.f - 2.f / (e + 1.f);
  return copysignf(t, x);
}

// Exchange ledger (measured, r2-r12): cross-WG producer->consumer handoff on
// gfx950 is ~2.9us REGARDLESS of mechanism (sys-scope stores/polls r6;
// broadcast r7 worse; line-spread r8 neutral; rate-cut r9 neutral; no-sc1
// atomics r10 not a meeting point; agent-RMW r11 neutral) and is INFLATED by
// any concurrent memory traffic (r5 saturating: wash; r12 throttled 1.1TB/s:
// +60us). => scan must run ALONE; 128 handoffs ~= 360us structural.
// r4 ERRATUM stands: sc0-only loads never observe remote stores (stale L1).
__device__ __forceinline__ void st_u64_sys(unsigned long long* p, unsigned long long v) {
  asm volatile("global_store_dwordx2 %0, %1, off sc0 sc1" :: "v"(p), "v"(v) : "memory");
}
__device__ __forceinline__ unsigned long long ld_u64_sys(const unsigned long long* p) {
  unsigned long long a;
  asm volatile("global_load_dwordx2 %0, %1, off sc0 sc1\n\ts_waitcnt vmcnt(0)"
               : "=&v"(a) : "v"(p) : "memory");
  return a;
}

#define GLDS16(gp, lp)                                                                 \
  __builtin_amdgcn_global_load_lds((const __attribute__((address_space(1))) void*)(gp),\
                                   (__attribute__((address_space(3))) void*)(lp), 16, 0, 0)

// ---------------- fp32 -> bf16 convert (x and y fused) ----------------
__global__ void cvt_xy(const float* __restrict__ x, const float* __restrict__ y,
                       unsigned short* __restrict__ xb, unsigned short* __restrict__ yb) {
  int i = (blockIdx.x * blockDim.x + threadIdx.x) * 4;
  const float* src;
  unsigned short* dst;
  int j;
  if (i < TEnc * HID) { src = x; dst = xb; j = i; }
  else { src = y; dst = yb; j = i - TEnc * HID; }
  float4 v = *(const float4*)(src + j);
  ushort4 o;
  o.x = f2bf(v.x); o.y = f2bf(v.y); o.z = f2bf(v.z); o.w = f2bf(v.w);
  *(ushort4*)(dst + j) = o;
}

// ---------------- BT-GEMM: C[M,N] = A[M,K](bf16) * B[N,K]^T(f32->bf16) + bias ----------------
template <int BN, int BK>
__global__ __launch_bounds__(256, 1) void gemm_bt(
    const unsigned short* __restrict__ Abf, const float* __restrict__ B,
    const float* __restrict__ bias, float* __restrict__ C, unsigned short* __restrict__ Cbf,
    int M, int N, int K) {
  constexpr int NF = BN / 16;
  constexpr int B4 = BN * BK / 1024;
  constexpr int AG = BK / 16;
  constexpr int KK = BK / 32;
  extern __shared__ char smem[];
  unsigned short* Al0 = (unsigned short*)smem;
  unsigned short* Al1 = Al0 + 128 * BK;
  unsigned short* Bl0 = Al1 + 128 * BK;
  unsigned short* Bl1 = Bl0 + BN * BK;

  const int tid = threadIdx.x;
  const int lane = tid & 63;
  const int wid = tid >> 6;
  const int m0 = blockIdx.x * 128;
  const int n0 = blockIdx.y * BN;
  const int NT = K / BK;

  float4 breg[B4];
  f32x4 acc[2][NF];
#pragma unroll
  for (int i = 0; i < 2; ++i)
#pragma unroll
    for (int j = 0; j < NF; ++j) acc[i][j] = (f32x4){0.f, 0.f, 0.f, 0.f};

  auto stageA = [&](int t, unsigned short* dst) {
    const unsigned short* Ab = Abf + (size_t)m0 * K + (size_t)t * BK;
#pragma unroll
    for (int g = 0; g < AG; ++g) {
      int elem = g * 2048 + tid * 8;
      int arow = elem / BK;
      int acol = elem - arow * BK;
      GLDS16(Ab + (size_t)arow * K + acol, (char*)dst + g * 4096 + wid * 1024);
    }
  };
  auto loadB = [&](int t) {
    const float* Bb = B + (size_t)t * BK;
#pragma unroll
    for (int p = 0; p < B4; ++p) {
      int e = (p * 256 + tid) * 4;
      int brow = e / BK;
      int bcol = e - brow * BK;
      int grow = n0 + brow;
      if (grow > N - 1) grow = N - 1;
      breg[p] = *(const float4*)(Bb + (size_t)grow * K + bcol);
    }
  };
  auto writeB = [&](unsigned short* dst) {
#pragma unroll
    for (int p = 0; p < B4; ++p) {
      ushort4 o;
      o.x = f2bf(breg[p].x); o.y = f2bf(breg[p].y);
      o.z = f2bf(breg[p].z); o.w = f2bf(breg[p].w);
      *(ushort4*)((char*)dst + (p * 256 + tid) * 8) = o;
    }
  };

  stageA(0, Al0);
  loadB(0);
  for (int t = 0; t < NT; ++t) {
    unsigned short* Ac = (t & 1) ? Al1 : Al0;
    unsigned short* Bc = (t & 1) ? Bl1 : Bl0;
    asm volatile("s_waitcnt vmcnt(0)" ::: "memory");
    writeB(Bc);
    __syncthreads();
    if (t + 1 < NT) {
      stageA(t + 1, (t & 1) ? Al0 : Al1);
      loadB(t + 1);
    }
    const int r0 = lane & 15;
    const int kb = (lane >> 4) * 8;
#pragma unroll
    for (int kk = 0; kk < KK; ++kk) {
      int ko = kk * 32 + kb;
      bf16x8 a0 = *(const bf16x8*)(Ac + (wid * 32 + r0) * BK + ko);
      bf16x8 a1 = *(const bf16x8*)(Ac + (wid * 32 + 16 + r0) * BK + ko);
#pragma unroll
      for (int nf = 0; nf < NF; ++nf) {
        bf16x8 bb = *(const bf16x8*)(Bc + (nf * 16 + r0) * BK + ko);
        acc[0][nf] = __builtin_amdgcn_mfma_f32_16x16x32_bf16(a0, bb, acc[0][nf], 0, 0, 0);
        acc[1][nf] = __builtin_amdgcn_mfma_f32_16x16x32_bf16(a1, bb, acc[1][nf], 0, 0, 0);
      }
    }
  }
  const int cc = lane & 15;
  const int rq = (lane >> 4) * 4;
#pragma unroll
  for (int mi = 0; mi < 2; ++mi) {
    int row = m0 + wid * 32 + mi * 16 + rq;
#pragma unroll
    for (int nf = 0; nf < NF; ++nf) {
      int col = n0 + nf * 16 + cc;
      if (col < N) {
        float bv = bias ? bias[col] : 0.f;
#pragma unroll
        for (int j = 0; j < 4; ++j) {
          float v = acc[mi][nf][j] + bv;
          if (C) C[(size_t)(row + j) * N + col] = v;
          if (Cbf) Cbf[(size_t)(row + j) * N + col] = f2bf(v);
        }
      }
    }
  }
}

// ---------------- encoder GEMM with fused GRU gates (h_prev = 0) ----------------
__global__ __launch_bounds__(256, 1) void gemm_enc(
    const unsigned short* __restrict__ Abf, const float* __restrict__ Wi,
    const float* __restrict__ bi, const float* __restrict__ bh,
    float* __restrict__ encH, unsigned short* __restrict__ encHbf) {
  constexpr int BN = 96, BK = 128, NF = 6, B4 = 12, AG = 8, KK = 4, K = 512;
  extern __shared__ char smem[];
  unsigned short* Al0 = (unsigned short*)smem;
  unsigned short* Al1 = Al0 + 128 * BK;
  unsigned short* Bl0 = Al1 + 128 * BK;
  unsigned short* Bl1 = Bl0 + BN * BK;

  const int tid = threadIdx.x;
  const int lane = tid & 63;
  const int wid = tid >> 6;
  const int m0 = blockIdx.x * 128;
  const int n0g = blockIdx.y * 32;
  const int NT = K / BK;

  float4 breg[B4];
  f32x4 acc[2][NF];
#pragma unroll
  for (int i = 0; i < 2; ++i)
#pragma unroll
    for (int j = 0; j < NF; ++j) acc[i][j] = (f32x4){0.f, 0.f, 0.f, 0.f};

  auto stageA = [&](int t, unsigned short* dst) {
    const unsigned short* Ab = Abf + (size_t)m0 * K + (size_t)t * BK;
#pragma unroll
    for (int g = 0; g < AG; ++g) {
      int elem = g * 2048 + tid * 8;
      int arow = elem >> 7;
      int acol = elem & 127;
      GLDS16(Ab + (size_t)arow * K + acol, (char*)dst + g * 4096 + wid * 1024);
    }
  };
  auto loadB = [&](int t) {
    const float* Bb = Wi + (size_t)t * BK;
#pragma unroll
    for (int p = 0; p < B4; ++p) {
      int e = (p * 256 + tid) * 4;
      int brow = e >> 7;
      int bcol = e & 127;
      int grow = (brow >> 5) * HID + n0g + (brow & 31);
      breg[p] = *(const float4*)(Bb + (size_t)grow * K + bcol);
    }
  };
  auto writeB = [&](unsigned short* dst) {
#pragma unroll
    for (int p = 0; p < B4; ++p) {
      ushort4 o;
      o.x = f2bf(breg[p].x); o.y = f2bf(breg[p].y);
      o.z = f2bf(breg[p].z); o.w = f2bf(breg[p].w);
      *(ushort4*)((char*)dst + (p * 256 + tid) * 8) = o;
    }
  };

  stageA(0, Al0);
  loadB(0);
  for (int t = 0; t < NT; ++t) {
    unsigned short* Ac = (t & 1) ? Al1 : Al0;
    unsigned short* Bc = (t & 1) ? Bl1 : Bl0;
    asm volatile("s_waitcnt vmcnt(0)" ::: "memory");
    writeB(Bc);
    __syncthreads();
    if (t + 1 < NT) {
      stageA(t + 1, (t & 1) ? Al0 : Al1);
      loadB(t + 1);
    }
    const int r0 = lane & 15;
    const int kb = (lane >> 4) * 8;
#pragma unroll
    for (int kk = 0; kk < KK; ++kk) {
      int ko = kk * 32 + kb;
      bf16x8 a0 = *(const bf16x8*)(Ac + (wid * 32 + r0) * BK + ko);
      bf16x8 a1 = *(const bf16x8*)(Ac + (wid * 32 + 16 + r0) * BK + ko);
#pragma unroll
      for (int nf = 0; nf < NF; ++nf) {
        bf16x8 bb = *(const bf16x8*)(Bc + (nf * 16 + r0) * BK + ko);
        acc[0][nf] = __builtin_amdgcn_mfma_f32_16x16x32_bf16(a0, bb, acc[0][nf], 0, 0, 0);
        acc[1][nf] = __builtin_amdgcn_mfma_f32_16x16x32_bf16(a1, bb, acc[1][nf], 0, 0, 0);
      }
    }
  }
  const int cc = lane & 15;
  const int rq = (lane >> 4) * 4;
#pragma unroll
  for (int mi = 0; mi < 2; ++mi) {
    int row = m0 + wid * 32 + mi * 16 + rq;
#pragma unroll
    for (int nfj = 0; nfj < 2; ++nfj) {
      int j = n0g + nfj * 16 + cc;
      float br_ = bi[j] + bh[j];
      float bz_ = bi[HID + j] + bh[HID + j];
      float bin_ = bi[2 * HID + j];
      float bhn_ = bh[2 * HID + j];
#pragma unroll
      for (int jj = 0; jj < 4; ++jj) {
        float r = sigmoidf_(acc[mi][nfj][jj] + br_);
        float z = sigmoidf_(acc[mi][nfj + 2][jj] + bz_);
        float n = tanh_fast(acc[mi][nfj + 4][jj] + bin_ + r * bhn_);
        float h = (1.f - z) * n;
        encH[(size_t)(row + jj) * HID + j] = h;
        encHbf[(size_t)(row + jj) * HID + j] = f2bf(h);
      }
    }
  }
}

// ---------------- sequential GRU scan: r6 champion EXACT (runs alone) ----------------
// 32 WGs, sys-scope packed tagged mailbox (2x256 u64, double-buffered by t&1),
// 256 stores/step, every thread polls ONE word. At the measured ~2.9us/step
// cross-WG handoff floor. NO co-resident work (r5/r12: any co-traffic
// inflates the exchange RTT). Own-dim recurrence fp32 in wave3's hreg.
__global__ __launch_bounds__(256, 1) void gru_scan(
    const float* __restrict__ Whd, const float* __restrict__ bhd,
    const float* __restrict__ giY, const float* __restrict__ h0,
    unsigned long long* __restrict__ hx,
    unsigned short* __restrict__ decSbf, unsigned short* __restrict__ concatbf) {
  __shared__ float hl[548];   // word w -> slot w + ((w>>7)<<2); 544 used
  __shared__ float dots[48];
  const int tid = threadIdx.x;
  const int lane = tid & 63, wid = tid >> 6;
  const int g = blockIdx.x;

  const int row16 = lane & 15;
  const int q = lane >> 4;
  float4 wreg[32];
  {
    int wrow = (wid < 3) ? wid : 0;
    const float* wr = Whd + ((size_t)wrow * HID + (size_t)g * 16 + row16) * HID + q * 128;
#pragma unroll
    for (int i = 0; i < 32; ++i) wreg[i] = *(const float4*)(wr + i * 4);
  }
  float bhr = 0.f, bhz = 0.f, bhn = 0.f, hreg = 0.f;
  if (wid == 3 && lane < 16) {
    int jj = g * 16 + lane;
    bhr = bhd[jj]; bhz = bhd[HID + jj]; bhn = bhd[2 * HID + jj];
    hreg = h0[jj];
  }
  {
    int w0 = tid * 2, w1 = tid * 2 + 1;
    hl[w0 + ((w0 >> 7) << 2)] = h0[w0];
    hl[w1 + ((w1 >> 7) << 2)] = h0[w1];
  }
  __syncthreads();

  for (int t = 0; t < TDec; ++t) {
    float gir = 0.f, giz = 0.f, gin = 0.f;
    if (wid < 3) {
      const float4* hp = (const float4*)hl;
      const int hb = q * 33;
      float p0 = 0.f, p1 = 0.f, p2 = 0.f, p3 = 0.f;
#pragma unroll
      for (int i = 0; i < 32; i += 4) {
        float4 ha = hp[hb + i], hv = hp[hb + i + 1], hc = hp[hb + i + 2], hd = hp[hb + i + 3];
        float4 wa = wreg[i], wb = wreg[i + 1], wc = wreg[i + 2], wd = wreg[i + 3];
        p0 += wa.x * ha.x + wa.y * ha.y + wa.z * ha.z + wa.w * ha.w;
        p1 += wb.x * hv.x + wb.y * hv.y + wb.z * hv.z + wb.w * hv.w;
        p2 += wc.x * hc.x + wc.y * hc.y + wc.z * hc.z + wc.w * hc.w;
        p3 += wd.x * hd.x + wd.y * hd.y + wd.z * hd.z + wd.w * hd.w;
      }
      float p = (p0 + p1) + (p2 + p3);
      p += __shfl_xor(p, 16);
      p += __shfl_xor(p, 32);
      if (lane < 16) dots[wid * 16 + lane] = p;
    } else if (lane < 16) {
      int jj = g * 16 + lane;
      const float* gi = giY + (size_t)t * THREE_H;
      gir = gi[jj]; giz = gi[HID + jj]; gin = gi[2 * HID + jj];  // hidden under dots
    }
    __syncthreads();  // dots ready; hl(t) reads done
    unsigned long long* hxB = hx + (size_t)(t & 1) * 256;
    if (wid == 3 && lane < 16) {
      int jj = g * 16 + lane;
      float r = sigmoidf_(gir + dots[lane] + bhr);
      float z = sigmoidf_(giz + dots[16 + lane] + bhz);
      float n = tanh_fast(gin + r * (dots[32 + lane] + bhn));
      float hn = (1.f - z) * n + z * hreg;
      hreg = hn;
      unsigned short hb16 = f2bf(hn);
      unsigned short hb_up = (unsigned short)__shfl_xor((int)hb16, 1);
      if ((lane & 1) == 0) {
        unsigned long long w = ((unsigned long long)(unsigned)(t + 1) << 32) |
                               ((unsigned)hb_up << 16) | (unsigned)hb16;
        st_u64_sys(hxB + g * 8 + (lane >> 1), w);
      }
      decSbf[(size_t)t * HID + jj] = hb16;
      concatbf[(size_t)t * 2 * HID + HID + jj] = hb16;
    }
    if (t == TDec - 1) break;
    {
      const unsigned long long* p0 = hxB + tid;
      const unsigned tag = (unsigned)(t + 1);
      unsigned long long v;
      int guard = 0;
      do { v = ld_u64_sys(p0); } while ((unsigned)(v >> 32) != tag && ++guard < (1 << 20));
      int w0 = tid * 2, w1 = tid * 2 + 1;
      hl[w0 + ((w0 >> 7) << 2)] = __uint_as_float(((unsigned)v & 0xFFFFu) << 16);
      hl[w1 + ((w1 >> 7) << 2)] = __uint_as_float((((unsigned)v >> 16) & 0xFFFFu) << 16);
    }
    __syncthreads();
  }
}

// ---------------- attention: fused decP + scores + softmax + context (r12-validated) ----------------
__global__ __launch_bounds__(256) void attn_ctx(const float* __restrict__ encP,
                                                const unsigned short* __restrict__ decSbf,
                                                const float* __restrict__ Ws,
                                                const float* __restrict__ battn,
                                                const float* __restrict__ vattn,
                                                const float* __restrict__ encH,
                                                unsigned short* __restrict__ concatbf) {
  __shared__ float dp[ADIM], vv[ADIM], pl[TEnc], dsr[HID];
  __shared__ float red[8];
  const int t = blockIdx.x, tid = threadIdx.x;
  {
    unsigned short u0 = decSbf[(size_t)t * HID + tid];
    unsigned short u1 = decSbf[(size_t)t * HID + tid + 256];
    dsr[tid] = __uint_as_float((unsigned)u0 << 16);
    dsr[tid + 256] = __uint_as_float((unsigned)u1 << 16);
  }
  if (tid < 64) *(float4*)(vv + tid * 4) = *(const float4*)(vattn + tid * 4);
  __syncthreads();
  // fused decP[a] = dot(Ws[a,:], decS[t,:]) + b_attn[a]
  {
    const float4* wr = (const float4*)(Ws + (size_t)tid * HID);
    const float4* hr = (const float4*)dsr;
    float s0 = 0.f, s1 = 0.f, s2 = 0.f, s3 = 0.f;
#pragma unroll 4
    for (int k = 0; k < 128; k += 4) {
      float4 w0 = wr[k], w1 = wr[k + 1], w2 = wr[k + 2], w3 = wr[k + 3];
      float4 h0 = hr[k], h1 = hr[k + 1], h2 = hr[k + 2], h3 = hr[k + 3];
      s0 += w0.x * h0.x + w0.y * h0.y + w0.z * h0.z + w0.w * h0.w;
      s1 += w1.x * h1.x + w1.y * h1.y + w1.z * h1.z + w1.w * h1.w;
      s2 += w2.x * h2.x + w2.y * h2.y + w2.z * h2.z + w2.w * h2.w;
      s3 += w3.x * h3.x + w3.y * h3.y + w3.z * h3.z + w3.w * h3.w;
    }
    dp[tid] = (s0 + s1) + (s2 + s3) + battn[tid];
  }
  __syncthreads();
  float s = 0.f;
  const float* ep = encP + (size_t)tid * ADIM;
#pragma unroll 4
  for (int a = 0; a < ADIM; a += 4) {
    float4 e4 = *(const float4*)(ep + a);
    s += vv[a] * tanh_fast(e4.x + dp[a]);
    s += vv[a + 1] * tanh_fast(e4.y + dp[a + 1]);
    s += vv[a + 2] * tanh_fast(e4.z + dp[a + 2]);
    s += vv[a + 3] * tanh_fast(e4.w + dp[a + 3]);
  }
  float m = s;
#pragma unroll
  for (int off = 32; off; off >>= 1) m = fmaxf(m, __shfl_xor(m, off));
  if ((tid & 63) == 0) red[tid >> 6] = m;
  __syncthreads();
  m = fmaxf(fmaxf(red[0], red[1]), fmaxf(red[2], red[3]));
  float p = __expf(s - m);
  pl[tid] = p;
  float sum = p;
#pragma unroll
  for (int off = 32; off; off >>= 1) sum += __shfl_xor(sum, off);
  if ((tid & 63) == 0) red[4 + (tid >> 6)] = sum;
  __syncthreads();
  float inv = 1.f / (red[4] + red[5] + red[6] + red[7]);
  float a0 = 0.f, a1 = 0.f;
  for (int e = 0; e < TEnc; ++e) {
    float pe = pl[e];
    a0 += pe * encH[(size_t)e * HID + tid];
    a1 += pe * encH[(size_t)e * HID + tid + 256];
  }
  concatbf[(size_t)t * 2 * HID + tid] = f2bf(a0 * inv);
  concatbf[(size_t)t * 2 * HID + tid + 256] = f2bf(a1 * inv);
}

extern "C" void kernel_launch(void* const* d_in, const int* in_sizes, int n_in,
                              void* d_out, int out_size, void* d_ws, size_t ws_size,
                              hipStream_t stream) {
  const float* x = (const float*)d_in[0];
  const float* y = (const float*)d_in[1];
  const float* Wi_e = (const float*)d_in[2];
  const float* bi_e = (const float*)d_in[4];
  const float* bh_e = (const float*)d_in[5];
  const float* Wi_d = (const float*)d_in[6];
  const float* Wh_d = (const float*)d_in[7];
  const float* bi_d = (const float*)d_in[8];
  const float* bh_d = (const float*)d_in[9];
  const float* Wh_attn = (const float*)d_in[10];
  const float* Ws_attn = (const float*)d_in[11];
  const float* b_attn = (const float*)d_in[12];
  const float* v_attn = (const float*)d_in[13];
  const float* W1 = (const float*)d_in[14];
  const float* b1 = (const float*)d_in[15];
  const float* W2 = (const float*)d_in[16];
  const float* b2 = (const float*)d_in[17];
  float* out = (float*)d_out;

  char* ws = (char*)d_ws;
  size_t off = 0;
  auto alloc = [&](size_t bytes) {
    char* p = ws + off;
    off += (bytes + 255) & ~(size_t)255;
    return p;
  };
  char* ctrl = alloc(4096);
  unsigned long long* hx = (unsigned long long*)ctrl;  // 2*256*8 = 4096
  unsigned short* Xbf = (unsigned short*)alloc((size_t)TEnc * HID * 2);
  unsigned short* Ybf = (unsigned short*)alloc((size_t)TDec * HID * 2);
  float* giY = (float*)alloc((size_t)TDec * THREE_H * 4);
  float* encH = (float*)alloc((size_t)TEnc * HID * 4);
  unsigned short* encHbf = (unsigned short*)alloc((size_t)TEnc * HID * 2);
  float* encP = (float*)alloc((size_t)TEnc * ADIM * 4);
  unsigned short* decSbf = (unsigned short*)alloc((size_t)TDec * HID * 2);
  unsigned short* concatbf = (unsigned short*)alloc((size_t)TDec * 2 * HID * 2);
  unsigned short* out1bf = (unsigned short*)alloc((size_t)TDec * 20000 * 2);

  hipMemsetAsync(ctrl, 0, 4096, stream);  // zero exchange tags

  auto* g32 = gemm_bt<32, 128>;
  auto* g80 = gemm_bt<80, 128>;
  auto* g64 = gemm_bt<64, 160>;
  const int smem32 = (128 + 32) * 128 * 2 * 2;      // 81920
  const int smem80 = (128 + 80) * 128 * 2 * 2;      // 106496
  const int smem64 = (128 + 64) * 160 * 2 * 2;      // 122880
  const int smemEnc = (128 + 96) * 128 * 2 * 2;     // 114688
  hipFuncSetAttribute((const void*)g32, hipFuncAttributeMaxDynamicSharedMemorySize, smem32);
  hipFuncSetAttribute((const void*)g80, hipFuncAttributeMaxDynamicSharedMemorySize, smem80);
  hipFuncSetAttribute((const void*)g64, hipFuncAttributeMaxDynamicSharedMemorySize, smem64);
  hipFuncSetAttribute((const void*)gemm_enc, hipFuncAttributeMaxDynamicSharedMemorySize, smemEnc);

  cvt_xy<<<(TEnc + TDec) * HID / 1024, 256, 0, stream>>>(x, y, Xbf, Ybf);
  // encoder GEMM + fused gates
  gemm_enc<<<dim3(2, 16), 256, smemEnc, stream>>>(Xbf, Wi_e, bi_e, bh_e, encH, encHbf);
  // encP = encH @ Wh_attn^T
  g32<<<dim3(2, 8), 256, smem32, stream>>>(encHbf, Wh_attn, nullptr, encP, nullptr, 256, 256, 512);
  // giY = Ybf @ Wi_d^T + bi_d
  g32<<<dim3(1, 48), 256, smem32, stream>>>(Ybf, Wi_d, bi_d, giY, nullptr, 128, 1536, 512);
  // sequential decoder: r6 champion scan, runs ALONE
  gru_scan<<<32, 256, 0, stream>>>(Wh_d, bh_d, giY, encH + 255 * HID, hx, decSbf, concatbf);
  // fused decP + attention + context
  attn_ctx<<<TDec, 256, 0, stream>>>(encP, decSbf, Ws_attn, b_attn, v_attn, encH, concatbf);
  // out1 = concat @ W1^T + b1 (store bf16)
  g80<<<dim3(1, 250), 256, smem80, stream>>>(concatbf, W1, b1, nullptr, out1bf, 128, 20000, 1024);
  // out = out1 @ W2^T + b2 (f32 B-stream, 800MB once)
  g64<<<dim3(1, 157), 256, smem64, stream>>>(out1bf, W2, b2, out, nullptr, 128, NVOC, 20000);
}